// Round 1
// baseline (880.925 us; speedup 1.0000x reference)
//
#include <hip/hip_runtime.h>
#include <stdint.h>
#include <stddef.h>

// sources (B,T,N,D) fp32, queries (L,D) fp32, layer_idx int scalar.
// out (B,T,D) fp32.  B*T = 32768, N = 9, D = 512 for this problem.
static constexpr int D = 512;
static constexpr int N = 9;
static constexpr float EPS = 1e-6f;

// v2 changes vs the 775 µs kernel:
//  1. bt_total unit fix: in_sizes is (very likely) BYTES -> the old
//     /(N*D) launched a 4x grid (131072 "bt"), streaming 2.416 GB of
//     arena poison and writing 256 MiB (192 MiB OOB). Correctness passed
//     because bt < 32768 was right. Now disambiguated via in_sizes[2]
//     (scalar layer_idx: 1 if element units, 4/8 if byte units).
//  2. Two-pass structure: no register-resident s0/s1 (was 72 VGPRs of
//     payload -> ~2 waves/SIMD). Pass 1 computes per-lane partials for
//     all 9 rows, then all 18 butterfly reduce chains run interleaved
//     (6 steps x 18 independent swizzles). Pass 2 re-reads the 18 KiB
//     tile (L2/L3-hot, zero extra HBM) for the alpha-weighted sum.
__global__ __launch_bounds__(256, 4) void block_attn(
    const float4* __restrict__ src4,
    const float4* __restrict__ q4,
    const int*   __restrict__ layer_idx,
    float4* __restrict__ out4,
    int bt_total)
{
    const int lane = threadIdx.x & 63;
    const int wave = threadIdx.x >> 6;
    const int bt   = blockIdx.x * 4 + wave;
    if (bt >= bt_total) return;

    const int li = layer_idx[0];
    const float4* qp = q4 + (size_t)li * (D / 4);
    const float4 w0 = qp[lane];
    const float4 w1 = qp[64 + lane];

    // lane owns floats {4*lane..+3} and {256+4*lane..+3} of each 512-row:
    // every access is a coalesced wave-wide dwordx4 (1 KiB/instruction).
    const float4* p = src4 + (size_t)bt * (size_t)(N * (D / 4)) + lane;

    // ---- pass 1: per-lane partials (ss = sum s^2, dt = dot(s, w)) ----
    float ss[N], dt[N];
#pragma unroll
    for (int n = 0; n < N; ++n) {
        const float4 a = p[n * (D / 4)];
        const float4 b = p[n * (D / 4) + 64];

        float s2 = a.x * a.x;
        s2 = fmaf(a.y, a.y, s2); s2 = fmaf(a.z, a.z, s2); s2 = fmaf(a.w, a.w, s2);
        s2 = fmaf(b.x, b.x, s2); s2 = fmaf(b.y, b.y, s2);
        s2 = fmaf(b.z, b.z, s2); s2 = fmaf(b.w, b.w, s2);

        float dd = a.x * w0.x;
        dd = fmaf(a.y, w0.y, dd); dd = fmaf(a.z, w0.z, dd); dd = fmaf(a.w, w0.w, dd);
        dd = fmaf(b.x, w1.x, dd); dd = fmaf(b.y, w1.y, dd);
        dd = fmaf(b.z, w1.z, dd); dd = fmaf(b.w, w1.w, dd);

        ss[n] = s2; dt[n] = dd;
    }

    // ---- 18 independent butterfly chains, interleaved per step ----
#pragma unroll
    for (int m = 1; m < 64; m <<= 1) {
#pragma unroll
        for (int n = 0; n < N; ++n) {
            ss[n] += __shfl_xor(ss[n], m, 64);
            dt[n] += __shfl_xor(dt[n], m, 64);
        }
    }

    // score = dot(s,w)/rms, rms = sqrt(mean(s^2)+eps)
    float score[N];
#pragma unroll
    for (int n = 0; n < N; ++n)
        score[n] = dt[n] * rsqrtf(ss[n] * (1.0f / 512.0f) + EPS);

    // softmax over N=9 (every lane holds all scores)
    float mx = score[0];
#pragma unroll
    for (int n = 1; n < N; ++n) mx = fmaxf(mx, score[n]);
    float asum = 0.f;
    float alpha[N];
#pragma unroll
    for (int n = 0; n < N; ++n) { alpha[n] = __expf(score[n] - mx); asum += alpha[n]; }
    const float inv = 1.0f / asum;

    // ---- pass 2: re-read (cache-hot) and accumulate h ----
    float4 h0 = {0.f, 0.f, 0.f, 0.f};
    float4 h1 = {0.f, 0.f, 0.f, 0.f};
#pragma unroll
    for (int n = 0; n < N; ++n) {
        const float an = alpha[n] * inv;
        const float4 a = p[n * (D / 4)];
        const float4 b = p[n * (D / 4) + 64];
        h0.x = fmaf(an, a.x, h0.x); h0.y = fmaf(an, a.y, h0.y);
        h0.z = fmaf(an, a.z, h0.z); h0.w = fmaf(an, a.w, h0.w);
        h1.x = fmaf(an, b.x, h1.x); h1.y = fmaf(an, b.y, h1.y);
        h1.z = fmaf(an, b.z, h1.z); h1.w = fmaf(an, b.w, h1.w);
    }

    float4* op = out4 + (size_t)bt * (D / 4);
    op[lane]      = h0;
    op[64 + lane] = h1;
}

extern "C" void kernel_launch(void* const* d_in, const int* in_sizes, int n_in,
                              void* d_out, int out_size, void* d_ws, size_t ws_size,
                              hipStream_t stream) {
    (void)n_in; (void)d_ws; (void)ws_size;
    const float4* src = (const float4*)d_in[0];
    const float4* q   = (const float4*)d_in[1];
    const int*    li  = (const int*)d_in[2];
    float4* out = (float4*)d_out;

    // Unit disambiguation: layer_idx is a single scalar, so its in_sizes
    // entry is 1 if sizes are element counts, 4 (int32) / 8 (int64) if bytes.
    const bool elem_units = (in_sizes[2] == 1);
    const long long src_elems = elem_units ? (long long)in_sizes[0]
                                           : (long long)in_sizes[0] / 4;
    const long long bt_total = src_elems / (long long)(N * D);   // = 32768

    const int blocks = (int)((bt_total + 3) / 4);   // 4 waves (one bt each) / block
    block_attn<<<blocks, 256, 0, stream>>>(src, q, li, out, (int)bt_total);
}

// Round 2
// 764.537 us; speedup vs baseline: 1.1522x; 1.1522x over previous
//
#include <hip/hip_runtime.h>
#include <stdint.h>
#include <stddef.h>

// sources (B,T,N,D) fp32, queries (L,D) fp32, layer_idx int scalar.
// out (B,T,D) fp32.  B*T = 32768, N = 9, D = 512 for this problem.
static constexpr int D = 512;
static constexpr int N = 9;
static constexpr float EPS = 1e-6f;

// v3 = round-0 single-read register-resident structure (the round-1
// two-pass re-read cost +105 us: the second 576 MiB read was charged at
// HBM rate, not cache-absorbed) + round-1's deferred reduction (all 18
// butterfly chains interleaved per step instead of 9 serialized 6-deep
// ds_swizzle chains -> ~2.2k stall cycles/wave removed).
__global__ __launch_bounds__(256) void block_attn(
    const float4* __restrict__ src4,
    const float4* __restrict__ q4,
    const int*   __restrict__ layer_idx,
    float4* __restrict__ out4,
    int bt_total)
{
    const int lane = threadIdx.x & 63;
    const int wave = threadIdx.x >> 6;
    const int bt   = blockIdx.x * 4 + wave;
    if (bt >= bt_total) return;

    const int li = layer_idx[0];
    const float4* qp = q4 + (size_t)li * (D / 4);
    const float4 w0 = qp[lane];
    const float4 w1 = qp[64 + lane];

    // lane owns floats {4*lane..+3} and {256+4*lane..+3} of each 512-row:
    // every access is a coalesced wave-wide dwordx4 (1 KiB/instruction).
    const float4* p = src4 + (size_t)bt * (size_t)(N * (D / 4)) + lane;

    float4 s0[N], s1[N];          // register-resident rows (single HBM read)
    float  ss[N], dt[N];          // per-lane partials

#pragma unroll
    for (int n = 0; n < N; ++n) {
        const float4 a = p[n * (D / 4)];
        const float4 b = p[n * (D / 4) + 64];
        s0[n] = a; s1[n] = b;

        float s2 = a.x * a.x;
        s2 = fmaf(a.y, a.y, s2); s2 = fmaf(a.z, a.z, s2); s2 = fmaf(a.w, a.w, s2);
        s2 = fmaf(b.x, b.x, s2); s2 = fmaf(b.y, b.y, s2);
        s2 = fmaf(b.z, b.z, s2); s2 = fmaf(b.w, b.w, s2);

        float dd = a.x * w0.x;
        dd = fmaf(a.y, w0.y, dd); dd = fmaf(a.z, w0.z, dd); dd = fmaf(a.w, w0.w, dd);
        dd = fmaf(b.x, w1.x, dd); dd = fmaf(b.y, w1.y, dd);
        dd = fmaf(b.z, w1.z, dd); dd = fmaf(b.w, w1.w, dd);

        ss[n] = s2; dt[n] = dd;
    }

    // ---- 18 independent butterfly chains, interleaved per step ----
    // (6 steps; each step issues 18 independent swizzle+add pairs, so the
    //  ~40-cycle ds_swizzle latency is hidden by ILP, not by occupancy)
#pragma unroll
    for (int m = 1; m < 64; m <<= 1) {
#pragma unroll
        for (int n = 0; n < N; ++n) {
            ss[n] += __shfl_xor(ss[n], m, 64);
            dt[n] += __shfl_xor(dt[n], m, 64);
        }
    }

    // score = dot(s,w)/rms, rms = sqrt(mean(s^2)+eps)
    float score[N];
#pragma unroll
    for (int n = 0; n < N; ++n)
        score[n] = dt[n] * rsqrtf(ss[n] * (1.0f / 512.0f) + EPS);

    // softmax over N=9 (every lane holds all scores)
    float mx = score[0];
#pragma unroll
    for (int n = 1; n < N; ++n) mx = fmaxf(mx, score[n]);
    float asum = 0.f;
    float alpha[N];
#pragma unroll
    for (int n = 0; n < N; ++n) { alpha[n] = __expf(score[n] - mx); asum += alpha[n]; }
    const float inv = 1.0f / asum;

    // h = sum_n alpha_n * sources_n  (from registers — no re-read)
    float4 h0 = {0.f, 0.f, 0.f, 0.f};
    float4 h1 = {0.f, 0.f, 0.f, 0.f};
#pragma unroll
    for (int n = 0; n < N; ++n) {
        const float an = alpha[n] * inv;
        h0.x = fmaf(an, s0[n].x, h0.x); h0.y = fmaf(an, s0[n].y, h0.y);
        h0.z = fmaf(an, s0[n].z, h0.z); h0.w = fmaf(an, s0[n].w, h0.w);
        h1.x = fmaf(an, s1[n].x, h1.x); h1.y = fmaf(an, s1[n].y, h1.y);
        h1.z = fmaf(an, s1[n].z, h1.z); h1.w = fmaf(an, s1[n].w, h1.w);
    }

    float4* op = out4 + (size_t)bt * (D / 4);
    op[lane]      = h0;
    op[64 + lane] = h1;
}

extern "C" void kernel_launch(void* const* d_in, const int* in_sizes, int n_in,
                              void* d_out, int out_size, void* d_ws, size_t ws_size,
                              hipStream_t stream) {
    (void)n_in; (void)d_ws; (void)ws_size;
    const float4* src = (const float4*)d_in[0];
    const float4* q   = (const float4*)d_in[1];
    const int*    li  = (const int*)d_in[2];
    float4* out = (float4*)d_out;

    // Unit disambiguation (harmless either way): layer_idx is a single
    // scalar, so its in_sizes entry is 1 if element units, 4/8 if bytes.
    const bool elem_units = (in_sizes[2] == 1);
    const long long src_elems = elem_units ? (long long)in_sizes[0]
                                           : (long long)in_sizes[0] / 4;
    const long long bt_total = src_elems / (long long)(N * D);   // = 32768

    const int blocks = (int)((bt_total + 3) / 4);   // 4 waves (one bt each) / block
    block_attn<<<blocks, 256, 0, stream>>>(src, q, li, out, (int)bt_total);
}